// Round 1
// 432.451 us; speedup vs baseline: 1.0639x; 1.0639x over previous
//
#include <hip/hip_runtime.h>

// MultiHeadAttention (mislabeled-einsum variant): per-position 16x16 head-mix.
// R4: port both GEMMs to the 256^2 / BK=64 / 8-wave / 8-phase counted-vmcnt
// template (T2 swizzle + T3/T4 counted vmcnt + T5 setprio). attn/cvt unchanged.

typedef unsigned int u32;
typedef unsigned short u16;
typedef __attribute__((ext_vector_type(4))) float f32x4;
typedef __attribute__((ext_vector_type(8))) short bf16x8;

__device__ __forceinline__ void async_copy16(const void* g, void* l) {
  __builtin_amdgcn_global_load_lds(
      (const __attribute__((address_space(1))) void*)g,
      (__attribute__((address_space(3))) void*)l, 16, 0, 0);
}

// round-half-up fp32->bf16, packed pair into one u32 (lo = a, hi = b)
__device__ __forceinline__ u32 pk_bf16(float a, float b) {
  u32 ua = (__builtin_bit_cast(u32, a) + 0x8000u) >> 16;
  u32 ub = (__builtin_bit_cast(u32, b) + 0x8000u) & 0xFFFF0000u;
  return ua | ub;
}
__device__ __forceinline__ float bflo(u32 u) { return __builtin_bit_cast(float, u << 16); }
__device__ __forceinline__ float bfhi(u32 u) { return __builtin_bit_cast(float, u & 0xFFFF0000u); }

struct F8 { float f[8]; };
__device__ __forceinline__ F8 unp8(uint4 u) {
  F8 r;
  r.f[0] = bflo(u.x); r.f[1] = bfhi(u.x);
  r.f[2] = bflo(u.y); r.f[3] = bfhi(u.y);
  r.f[4] = bflo(u.z); r.f[5] = bfhi(u.z);
  r.f[6] = bflo(u.w); r.f[7] = bfhi(u.w);
  return r;
}

// ---- weight conversion: 4 matrices of 1024x1024 fp32 -> bf16 -------------
__global__ void cvt_w4(const float* __restrict__ s0, const float* __restrict__ s1,
                       const float* __restrict__ s2, const float* __restrict__ s3,
                       u16* __restrict__ dst) {
  int z = blockIdx.y;
  const float* s = (z == 0) ? s0 : (z == 1) ? s1 : (z == 2) ? s2 : s3;
  u16* d = dst + (size_t)z * (1024 * 1024);
  int i = (blockIdx.x * 256 + threadIdx.x) * 4;
  float4 f = *(const float4*)(s + i);
  uint2 u;
  u.x = pk_bf16(f.x, f.y);
  u.y = pk_bf16(f.z, f.w);
  *(uint2*)(d + i) = u;
}

// ---- input conversion: q,k,v [16777216 fp32 each] -> bf16 -----------------
__global__ void cvt_in3(const float* __restrict__ s0, const float* __restrict__ s1,
                        const float* __restrict__ s2, u16* __restrict__ dst) {
  int z = blockIdx.y;
  const float* s = (z == 0) ? s0 : (z == 1) ? s1 : s2;
  u16* d = dst + (size_t)z * 16777216;
  int i = (blockIdx.x * 256 + threadIdx.x) * 4;
  float4 f = *(const float4*)(s + i);
  uint2 u;
  u.x = pk_bf16(f.x, f.y);
  u.y = pk_bf16(f.z, f.w);
  *(uint2*)(d + i) = u;
}

// ===========================================================================
// 256x256-tile, BK=64, 8-wave (2Mx4N), 8-phase counted-vmcnt GEMM.
// C[gm0:+256, gn0:+256] = A[.,1024] @ B[.,1024]^T + bias.
// LDS 128 KiB: A bufs @ elem 0 / 16384, B bufs @ 32768 / 49152 (each 256x64).
// Swizzle: LDS[row][c'] holds G[row][c' ^ ((row&7)<<3)] (16B-chunk XOR) --
// global_load_lds writes linearly, so the SOURCE col is pre-swizzled and the
// ds_read applies the same XOR (both-sides involution).
// Staging half-regions chosen by read deadline:
//   A-H0: rows with (row%128)<64  (read in phase p0 of a tile)
//   A-H1: (row%128)>=64           (read in p2)
//   B-H0: (row%64)<32             (read in p0, frags held to p2)
//   B-H1: (row%64)>=32            (read in p1, held to p3)
// Per-tile stage order A-H0,B-H0,A-H1,B-H1 at phases P+1..P+4 relative to the
// same-buffer compute at P..P+3 => every stage lands in LDS whose last read
// was >= 1 phase earlier (WAR safe across the phase barrier).
// vmcnt(6) at phases 3 and 7 keeps exactly 3 half-tiles (6 loads) in flight
// and guarantees the next tile is fully staged before its first ds_read.
// ===========================================================================

#define BAR() asm volatile("s_barrier" ::: "memory")
#define VMC(n) asm volatile("s_waitcnt vmcnt(" #n ")" ::: "memory")

template <bool OUTBF>
__device__ __forceinline__ void gemm256_8p(
    const u16* __restrict__ A, const u16* __restrict__ Bm,
    const float* __restrict__ bias, void* __restrict__ Cp,
    int gm0, int gn0, u16* sm) {
  const int tid = threadIdx.x;
  const int lane = tid & 63;
  const int w = tid >> 6;
  const int wm = w >> 2, wn = w & 3;       // 2 x 4 wave grid
  const int wr0 = wm * 128, wc0 = wn * 64; // per-wave 128x64 output
  const int lr = lane & 15, quad = lane >> 4;

  // staging decode: thread covers row chunk (sr, sc) of each 8KB load
  const int sr = tid >> 3;   // 0..63 (row within 64-row stripe)
  const int sc = tid & 7;    // 16B chunk within 128B row

  f32x4 acc[8][4];
#pragma unroll
  for (int i = 0; i < 8; i++)
#pragma unroll
    for (int j = 0; j < 4; j++) acc[i][j] = (f32x4){0.f, 0.f, 0.f, 0.f};

  bf16x8 aA[4][2];  // current A-half frags (4 mi x 2 kk)
  bf16x8 bB[4][2];  // all-B frags (4 ni x 2 kk), halves filled p0/p1, held

// -- staging: A-half h of tile T into buffer buf (2 x global_load_lds) ------
#define STAGE_A(buf, h, T) do {                                              \
    int k0_ = ((T) & 15) * 64;                                               \
    u16* lb_ = sm + (buf) * 16384;                                           \
    _Pragma("unroll")                                                        \
    for (int ld_ = 0; ld_ < 2; ld_++) {                                      \
      int row_ = ld_ * 128 + (h) * 64 + sr;      /* (row%128)<64 iff h==0 */ \
      int cs_ = (sc ^ (row_ & 7)) * 8;           /* pre-swizzled source */   \
      async_copy16(A + (size_t)(gm0 + row_) * 1024 + k0_ + cs_,              \
                   lb_ + row_ * 64 + sc * 8);                                \
    }                                                                        \
  } while (0)

// -- staging: B-half bh (row%64 stripe) of tile T into buffer buf -----------
#define STAGE_B(buf, bh, T) do {                                             \
    int k0_ = ((T) & 15) * 64;                                               \
    u16* lb_ = sm + 32768 + (buf) * 16384;                                   \
    _Pragma("unroll")                                                        \
    for (int ld_ = 0; ld_ < 2; ld_++) {                                      \
      int ri_ = ld_ * 64 + sr;                                               \
      int row_ = ((ri_ >> 5) << 6) + (bh) * 32 + (ri_ & 31);                 \
      int cs_ = (sc ^ (row_ & 7)) * 8;                                       \
      async_copy16(Bm + (size_t)(gn0 + row_) * 1024 + k0_ + cs_,             \
                   lb_ + row_ * 64 + sc * 8);                                \
    }                                                                        \
  } while (0)

// -- ds_read A frags for half mh (mi = mh*4 .. mh*4+3), swizzled ------------
#define READ_A(mh, buf) do {                                                 \
    const u16* lb_ = sm + (buf) * 16384;                                     \
    _Pragma("unroll")                                                        \
    for (int m4_ = 0; m4_ < 4; m4_++)                                        \
      _Pragma("unroll")                                                      \
      for (int kk_ = 0; kk_ < 2; kk_++) {                                    \
        int row_ = wr0 + ((mh) * 4 + m4_) * 16 + lr;                         \
        aA[m4_][kk_] = *(const bf16x8*)(lb_ + row_ * 64 +                    \
                         (((kk_ * 4 + quad) ^ (row_ & 7)) * 8));             \
      }                                                                      \
  } while (0)

#define READ_B(nh, buf) do {                                                 \
    const u16* lb_ = sm + 32768 + (buf) * 16384;                             \
    _Pragma("unroll")                                                        \
    for (int n2_ = 0; n2_ < 2; n2_++)                                        \
      _Pragma("unroll")                                                      \
      for (int kk_ = 0; kk_ < 2; kk_++) {                                    \
        int row_ = wc0 + ((nh) * 2 + n2_) * 16 + lr;                         \
        bB[(nh) * 2 + n2_][kk_] = *(const bf16x8*)(lb_ + row_ * 64 +         \
                         (((kk_ * 4 + quad) ^ (row_ & 7)) * 8));             \
      }                                                                      \
  } while (0)

// -- one quadrant: 16 MFMA (4 mi x 2 ni x 2 kk), setprio-wrapped ------------
#define MFMA16(mh, nh) do {                                                  \
    __builtin_amdgcn_s_setprio(1);                                           \
    _Pragma("unroll")                                                        \
    for (int m4_ = 0; m4_ < 4; m4_++)                                        \
      _Pragma("unroll")                                                      \
      for (int n2_ = 0; n2_ < 2; n2_++)                                      \
        _Pragma("unroll")                                                    \
        for (int kk_ = 0; kk_ < 2; kk_++)                                    \
          acc[(mh) * 4 + m4_][(nh) * 2 + n2_] =                              \
              __builtin_amdgcn_mfma_f32_16x16x32_bf16(                       \
                  aA[m4_][kk_], bB[(nh) * 2 + n2_][kk_],                     \
                  acc[(mh) * 4 + m4_][(nh) * 2 + n2_], 0, 0, 0);             \
    __builtin_amdgcn_s_setprio(0);                                           \
  } while (0)

  // ---- prologue: tile0 fully + tile1 {A0,B0,A1}; leave 6 loads in flight
  STAGE_A(0, 0, 0); STAGE_B(0, 0, 0); STAGE_A(0, 1, 0); STAGE_B(0, 1, 0);
  VMC(4);
  STAGE_A(1, 0, 1); STAGE_B(1, 0, 1); STAGE_A(1, 1, 1);
  VMC(6);   // tile0 fully landed; in flight: tile1.{A0,B0,A1}
  BAR();

  // ---- main loop: 8 iterations x (2 K-tiles = 8 phases) --------------------
  for (int i = 0; i < 8; i++) {
    const int T1 = 2 * i + 1, T2 = 2 * i + 2, T3 = 2 * i + 3;
    // phase 0: tile 2i (buf0), quadrant (mh0, nh0)
    READ_A(0, 0); READ_B(0, 0);
    STAGE_B(1, 1, T1);
    BAR(); MFMA16(0, 0); BAR();
    // phase 1: quadrant (0,1) -- reuse aA, read B-H1
    READ_B(1, 0);
    STAGE_A(0, 0, T2);
    BAR(); MFMA16(0, 1); BAR();
    // phase 2: quadrant (1,0) -- read A-H1, reuse held B-H0 frags
    READ_A(1, 0);
    STAGE_B(0, 0, T2);
    BAR(); MFMA16(1, 0); BAR();
    // phase 3: quadrant (1,1); counted vmcnt -> tile 2i+1 fully landed
    STAGE_A(0, 1, T2);
    VMC(6);
    BAR(); MFMA16(1, 1); BAR();
    // phase 4: tile 2i+1 (buf1), quadrant (0,0)
    READ_A(0, 1); READ_B(0, 1);
    STAGE_B(0, 1, T2);
    BAR(); MFMA16(0, 0); BAR();
    // phase 5
    READ_B(1, 1);
    STAGE_A(1, 0, T3);
    BAR(); MFMA16(0, 1); BAR();
    // phase 6
    READ_A(1, 1);
    STAGE_B(1, 0, T3);
    BAR(); MFMA16(1, 0); BAR();
    // phase 7: counted vmcnt -> tile 2i+2 fully landed
    STAGE_A(1, 1, T3);
    VMC(6);
    BAR(); MFMA16(1, 1); BAR();
  }
  VMC(0);  // drain wrap-around junk stages before LDS goes out of scope

  // ---- epilogue: row = gm0+wr0+mi*16+quad*4+r, col = gn0+wc0+ni*16+lr -----
#pragma unroll
  for (int ni = 0; ni < 4; ni++) {
    int col = gn0 + wc0 + ni * 16 + lr;
    float bv = bias[col];
#pragma unroll
    for (int mi = 0; mi < 8; mi++) {
      int row = gm0 + wr0 + mi * 16 + quad * 4;
#pragma unroll
      for (int r = 0; r < 4; r++) {
        float val = acc[mi][ni][r] + bv;
        if constexpr (OUTBF) {
          ((u16*)Cp)[(size_t)(row + r) * 1024 + col] =
              (u16)((__builtin_bit_cast(u32, val) + 0x8000u) >> 16);
        } else {
          ((float*)Cp)[(size_t)(row + r) * 1024 + col] = val;
        }
      }
    }
  }
#undef STAGE_A
#undef STAGE_B
#undef READ_A
#undef READ_B
#undef MFMA16
}

// fused QKV projection, 8-phase path. 768 blocks (64m x 4n x 3z), 512 thr.
// XCD c = lin&7 owns m-strips [8c, 8c+8); z outermost so W stays hot; n
// fastest within an m-tile for A-panel reuse.
__global__ __launch_bounds__(512, 2) void gemm_qkv8(
    const u16* __restrict__ X, const u16* __restrict__ W,
    const float* __restrict__ b0, const float* __restrict__ b1,
    const float* __restrict__ b2, u16* __restrict__ out) {
  __shared__ alignas(16) u16 sm[65536];
  const int lin = blockIdx.x;
  const int c = lin & 7;        // XCD
  const int i = lin >> 3;       // 0..95
  const int z = i >> 5;         // tensor 0..2
  const int r = i & 31;
  const int m = c * 8 + (r >> 2);
  const int n = r & 3;
  const float* bias = (z == 0) ? b0 : (z == 1) ? b1 : b2;
  gemm256_8p<true>(X + (size_t)z * 16777216, W + (size_t)z * 1048576, bias,
                   out + (size_t)z * 16777216, m * 256, n * 256, sm);
}

__global__ __launch_bounds__(512, 2) void gemm_o8(
    const u16* __restrict__ X, const u16* __restrict__ W,
    const float* __restrict__ bias, float* __restrict__ C) {
  __shared__ alignas(16) u16 sm[65536];
  const int lin = blockIdx.x;   // 0..255
  const int c = lin & 7;
  const int i = lin >> 3;       // 0..31
  const int m = c * 8 + (i >> 2);
  const int n = i & 3;
  gemm256_8p<false>(X, W, bias, C, m * 256, n * 256, sm);
}

// ---- legacy 128^2 GEMM tile (kept only for the fp32-A fallback path) ------
template <bool AF32, bool OUTBF>
__device__ __forceinline__ void gemm_tile(const void* __restrict__ Ap,
                                          const u16* __restrict__ Bp,
                                          const float* __restrict__ bias,
                                          void* __restrict__ Cp,
                                          int m0, int n0, u16* As, u16* Bs) {
  constexpr int KD = 1024;
  constexpr int ND = 1024;
  const int t = threadIdx.x;
  const int lane = t & 63, w = t >> 6;
  const int wr = (w >> 1) * 64, wc = (w & 1) * 64;
  const int lr = lane & 15, quad = lane >> 4;
  f32x4 acc[4][4] = {};

  for (int k0 = 0; k0 < KD; k0 += 32) {
    __syncthreads();
#pragma unroll
    for (int i = 0; i < 2; i++) {
      int c = i * 256 + t;
      int r = c >> 2, c8 = (c & 3) * 8;
      async_copy16(Bp + ((size_t)(n0 + r) * KD + k0 + c8), &Bs[c * 8]);
    }
    if constexpr (AF32) {
      const float* Af = (const float*)Ap;
      const int r = t >> 2, c8 = (t & 3) * 8;
      const float4* s0 = (const float4*)(Af + (size_t)(m0 + r) * KD + k0 + c8);
      const float4* s1 = (const float4*)(Af + (size_t)(m0 + 64 + r) * KD + k0 + c8);
      float4 f0 = s0[0], f1 = s0[1];
      float4 f2 = s1[0], f3 = s1[1];
      uint4 u0 = { pk_bf16(f0.x, f0.y), pk_bf16(f0.z, f0.w),
                   pk_bf16(f1.x, f1.y), pk_bf16(f1.z, f1.w) };
      uint4 u1 = { pk_bf16(f2.x, f2.y), pk_bf16(f2.z, f2.w),
                   pk_bf16(f3.x, f3.y), pk_bf16(f3.z, f3.w) };
      *(uint4*)&As[t * 8] = u0;
      *(uint4*)&As[(256 + t) * 8] = u1;
    } else {
      const u16* Ab = (const u16*)Ap;
#pragma unroll
      for (int i = 0; i < 2; i++) {
        int c = i * 256 + t;
        int r = c >> 2, c8 = (c & 3) * 8;
        async_copy16(Ab + ((size_t)(m0 + r) * KD + k0 + c8), &As[c * 8]);
      }
    }
    __syncthreads();

    bf16x8 af[4], bfr[4];
#pragma unroll
    for (int mi = 0; mi < 4; mi++)
      af[mi] = *(const bf16x8*)&As[(wr + mi * 16 + lr) * 32 + quad * 8];
#pragma unroll
    for (int ni = 0; ni < 4; ni++)
      bfr[ni] = *(const bf16x8*)&Bs[(wc + ni * 16 + lr) * 32 + quad * 8];
#pragma unroll
    for (int mi = 0; mi < 4; mi++)
#pragma unroll
      for (int ni = 0; ni < 4; ni++)
        acc[mi][ni] = __builtin_amdgcn_mfma_f32_16x16x32_bf16(af[mi], bfr[ni], acc[mi][ni], 0, 0, 0);
  }

#pragma unroll
  for (int ni = 0; ni < 4; ni++) {
    int col = n0 + wc + ni * 16 + lr;
    float bv = bias[col];
#pragma unroll
    for (int mi = 0; mi < 4; mi++) {
      int row = m0 + wr + mi * 16 + quad * 4;
#pragma unroll
      for (int r = 0; r < 4; r++) {
        float val = acc[mi][ni][r] + bv;
        if constexpr (OUTBF) {
          ((u16*)Cp)[(size_t)(row + r) * ND + col] =
              (u16)((__builtin_bit_cast(u32, val) + 0x8000u) >> 16);
        } else {
          ((float*)Cp)[(size_t)(row + r) * ND + col] = val;
        }
      }
    }
  }
}

template <bool AF32>
__global__ __launch_bounds__(256) void gemm_qkv(
    const void* __restrict__ a0, const void* __restrict__ a1, const void* __restrict__ a2,
    const u16* __restrict__ W, const float* __restrict__ b0, const float* __restrict__ b1,
    const float* __restrict__ b2, u16* __restrict__ out) {
  __shared__ alignas(16) u16 As[128 * 32];
  __shared__ alignas(16) u16 Bs[128 * 32];
  const int lin = blockIdx.x;
  const int c = lin & 7;
  const int i = lin >> 3;
  const int z = i >> 7;
  const int r = i & 127;
  const int m = c * 16 + (r >> 3);
  const int n = r & 7;
  const void* A = (z == 0) ? a0 : (z == 1) ? a1 : a2;
  const float* bias = (z == 0) ? b0 : (z == 1) ? b1 : b2;
  gemm_tile<AF32, true>(A, W + (size_t)z * 1048576, bias, out + (size_t)z * 16777216,
                        m * 128, n * 128, As, Bs);
}

// ---- per-position head-mix attention (unchanged, verified) ----------------
__global__ __launch_bounds__(256) void attn_mix(
    const u16* __restrict__ Q, const u16* __restrict__ K,
    const u16* __restrict__ V, const int* __restrict__ mask,
    u16* __restrict__ X) {
  constexpr int RS = 72;
  __shared__ alignas(16) u16 qs[4][16 * RS];
  __shared__ alignas(16) u16 ks[4][16 * RS];
  __shared__ alignas(16) u16 vs[4][16 * RS];

  const int w = threadIdx.x >> 6;
  const int lane = threadIdx.x & 63;
  const int p = blockIdx.x * 4 + w;
  const size_t base = (size_t)p * 1024;

  {
    const uint4* Qg = (const uint4*)(Q + base);
    const uint4* Kg = (const uint4*)(K + base);
    const uint4* Vg = (const uint4*)(V + base);
#pragma unroll
    for (int h = 0; h < 2; h++) {
      int j = h * 64 + lane;
      int off = (j >> 3) * RS + (j & 7) * 8;
      *(uint4*)&qs[w][off] = Qg[j];
      *(uint4*)&ks[w][off] = Kg[j];
      *(uint4*)&vs[w][off] = Vg[j];
    }
  }
  const int mk = mask[p];

  const int qh = lane >> 2, g = lane & 3;
  float e0 = 0.f, e1 = 0.f, e2 = 0.f, e3 = 0.f;
  {
    const u16* qr = &qs[w][qh * RS];
    const u16* k0r = &ks[w][(g * 4 + 0) * RS];
    const u16* k1r = &ks[w][(g * 4 + 1) * RS];
    const u16* k2r = &ks[w][(g * 4 + 2) * RS];
    const u16* k3r = &ks[w][(g * 4 + 3) * RS];
#pragma unroll
    for (int c = 0; c < 8; c++) {
      F8 qf = unp8(*(const uint4*)&qr[c * 8]);
      F8 ka = unp8(*(const uint4*)&k0r[c * 8]);
      F8 kb = unp8(*(const uint4*)&k1r[c * 8]);
      F8 kc = unp8(*(const uint4*)&k2r[c * 8]);
      F8 kd = unp8(*(const uint4*)&k3r[c * 8]);
#pragma unroll
      for (int j = 0; j < 8; j++) {
        e0 += qf.f[j] * ka.f[j];
        e1 += qf.f[j] * kb.f[j];
        e2 += qf.f[j] * kc.f[j];
        e3 += qf.f[j] * kd.f[j];
      }
    }
  }
  const float sc = mk ? 0.03125f : 0.0f;
  float v0 = e0 * sc, v1 = e1 * sc, v2 = e2 * sc, v3 = e3 * sc;
  float mx = fmaxf(fmaxf(v0, v1), fmaxf(v2, v3));
  mx = fmaxf(mx, __shfl_xor(mx, 1, 64));
  mx = fmaxf(mx, __shfl_xor(mx, 2, 64));
  float p0 = __expf(v0 - mx), p1 = __expf(v1 - mx), p2 = __expf(v2 - mx), p3 = __expf(v3 - mx);
  float s = p0 + p1 + p2 + p3;
  s += __shfl_xor(s, 1, 64);
  s += __shfl_xor(s, 2, 64);
  float inv = 1.0f / s;
  float a0 = p0 * inv, a1 = p1 * inv, a2 = p2 * inv, a3 = p3 * inv;

  float xa[16];
#pragma unroll
  for (int i = 0; i < 16; i++) xa[i] = 0.f;
#pragma unroll
  for (int g2 = 0; g2 < 4; g2++) {
    int src = (lane & ~3) | g2;
    float w0 = __shfl(a0, src, 64);
    float w1 = __shfl(a1, src, 64);
    float w2 = __shfl(a2, src, 64);
    float w3 = __shfl(a3, src, 64);
    const float wv[4] = { w0, w1, w2, w3 };
#pragma unroll
    for (int j4 = 0; j4 < 4; j4++) {
      int kh = g2 * 4 + j4;
      float wgt = wv[j4];
      F8 va = unp8(*(const uint4*)&vs[w][kh * RS + g * 16]);
      F8 vb = unp8(*(const uint4*)&vs[w][kh * RS + g * 16 + 8]);
#pragma unroll
      for (int j = 0; j < 8; j++) {
        xa[j] += wgt * va.f[j];
        xa[8 + j] += wgt * vb.f[j];
      }
    }
  }
  uint4 o0 = { pk_bf16(xa[0], xa[1]), pk_bf16(xa[2], xa[3]),
               pk_bf16(xa[4], xa[5]), pk_bf16(xa[6], xa[7]) };
  uint4 o1 = { pk_bf16(xa[8], xa[9]), pk_bf16(xa[10], xa[11]),
               pk_bf16(xa[12], xa[13]), pk_bf16(xa[14], xa[15]) };
  uint4* Xp = (uint4*)(X + base);
  Xp[lane * 2] = o0;
  Xp[lane * 2 + 1] = o1;
}

extern "C" void kernel_launch(void* const* d_in, const int* in_sizes, int n_in,
                              void* d_out, int out_size, void* d_ws, size_t ws_size,
                              hipStream_t stream) {
  const float* q    = (const float*)d_in[0];
  const float* k    = (const float*)d_in[1];
  const float* v    = (const float*)d_in[2];
  const int*   mask = (const int*)d_in[3];
  const float* Wq   = (const float*)d_in[4];
  const float* bq   = (const float*)d_in[5];
  const float* Wk   = (const float*)d_in[6];
  const float* bk   = (const float*)d_in[7];
  const float* Wv   = (const float*)d_in[8];
  const float* bv   = (const float*)d_in[9];
  const float* Wo   = (const float*)d_in[10];
  const float* bo   = (const float*)d_in[11];

  u16* wsb = (u16*)d_ws;
  const bool big = ws_size >= 209715200ull;  // 200 MiB path

  if (big) {
    // layout (u16 elems): Wqkv[3M] Wo[1M] qb/kb/vb[3x16.78M] Q/K/V[3x16.78M]; X aliases qb
    u16* Wqkv = wsb;
    u16* Wob  = wsb + 3145728;
    u16* qb   = wsb + 4194304;
    u16* Qb   = wsb + 54525952;
    u16* Kb   = Qb + 16777216;
    u16* Vb   = Kb + 16777216;
    u16* Xb   = qb;  // qb/kb/vb dead after gemm_qkv8
    cvt_w4<<<dim3(1024, 4), 256, 0, stream>>>(Wq, Wk, Wv, Wo, wsb);
    cvt_in3<<<dim3(16384, 3), 256, 0, stream>>>(q, k, v, qb);
    gemm_qkv8<<<768, 512, 0, stream>>>(qb, Wqkv, bq, bk, bv, Qb);
    attn_mix<<<4096, 256, 0, stream>>>(Qb, Kb, Vb, mask, Xb);
    gemm_o8<<<256, 512, 0, stream>>>(Xb, Wob, bo, (float*)d_out);
  } else {
    // fallback: fp32-A in-staging path (142.6 MB)
    u16* Wqkv = wsb;
    u16* Wob  = wsb + 3145728;
    u16* Qb   = wsb + 4194304;
    u16* Kb   = Qb + 16777216;
    u16* Vb   = Kb + 16777216;
    u16* Xb   = Vb + 16777216;
    cvt_w4<<<dim3(1024, 4), 256, 0, stream>>>(Wq, Wk, Wv, Wo, wsb);
    gemm_qkv<true><<<3072, 256, 0, stream>>>(q, k, v, Wqkv, bq, bk, bv, Qb);
    attn_mix<<<4096, 256, 0, stream>>>(Qb, Kb, Vb, mask, Xb);
    gemm_o8<<<256, 512, 0, stream>>>(Xb, Wob, bo, (float*)d_out);
  }
}

// Round 2
// 410.546 us; speedup vs baseline: 1.1207x; 1.0534x over previous
//
#include <hip/hip_runtime.h>

// MultiHeadAttention (mislabeled-einsum variant): per-position 16x16 head-mix.
// R5: LDS-repacked coalesced GEMM epilogue (fixes 2x write amplification +
// 1024 scattered stores/CU), drop mid-prologue VMC(4). Loop/schedule unchanged.

typedef unsigned int u32;
typedef unsigned short u16;
typedef __attribute__((ext_vector_type(4))) float f32x4;
typedef __attribute__((ext_vector_type(8))) short bf16x8;

__device__ __forceinline__ void async_copy16(const void* g, void* l) {
  __builtin_amdgcn_global_load_lds(
      (const __attribute__((address_space(1))) void*)g,
      (__attribute__((address_space(3))) void*)l, 16, 0, 0);
}

// round-half-up fp32->bf16, packed pair into one u32 (lo = a, hi = b)
__device__ __forceinline__ u32 pk_bf16(float a, float b) {
  u32 ua = (__builtin_bit_cast(u32, a) + 0x8000u) >> 16;
  u32 ub = (__builtin_bit_cast(u32, b) + 0x8000u) & 0xFFFF0000u;
  return ua | ub;
}
__device__ __forceinline__ float bflo(u32 u) { return __builtin_bit_cast(float, u << 16); }
__device__ __forceinline__ float bfhi(u32 u) { return __builtin_bit_cast(float, u & 0xFFFF0000u); }

struct F8 { float f[8]; };
__device__ __forceinline__ F8 unp8(uint4 u) {
  F8 r;
  r.f[0] = bflo(u.x); r.f[1] = bfhi(u.x);
  r.f[2] = bflo(u.y); r.f[3] = bfhi(u.y);
  r.f[4] = bflo(u.z); r.f[5] = bfhi(u.z);
  r.f[6] = bflo(u.w); r.f[7] = bfhi(u.w);
  return r;
}

// ---- weight conversion: 4 matrices of 1024x1024 fp32 -> bf16 -------------
__global__ void cvt_w4(const float* __restrict__ s0, const float* __restrict__ s1,
                       const float* __restrict__ s2, const float* __restrict__ s3,
                       u16* __restrict__ dst) {
  int z = blockIdx.y;
  const float* s = (z == 0) ? s0 : (z == 1) ? s1 : (z == 2) ? s2 : s3;
  u16* d = dst + (size_t)z * (1024 * 1024);
  int i = (blockIdx.x * 256 + threadIdx.x) * 4;
  float4 f = *(const float4*)(s + i);
  uint2 u;
  u.x = pk_bf16(f.x, f.y);
  u.y = pk_bf16(f.z, f.w);
  *(uint2*)(d + i) = u;
}

// ---- input conversion: q,k,v [16777216 fp32 each] -> bf16 -----------------
__global__ void cvt_in3(const float* __restrict__ s0, const float* __restrict__ s1,
                        const float* __restrict__ s2, u16* __restrict__ dst) {
  int z = blockIdx.y;
  const float* s = (z == 0) ? s0 : (z == 1) ? s1 : s2;
  u16* d = dst + (size_t)z * 16777216;
  int i = (blockIdx.x * 256 + threadIdx.x) * 4;
  float4 f = *(const float4*)(s + i);
  uint2 u;
  u.x = pk_bf16(f.x, f.y);
  u.y = pk_bf16(f.z, f.w);
  *(uint2*)(d + i) = u;
}

// ===========================================================================
// 256x256-tile, BK=64, 8-wave (2Mx4N), 8-phase counted-vmcnt GEMM.
// (See R4 comments for schedule derivation.) R5 adds an LDS-repacked epilogue:
// acc -> LDS (quad-XOR swizzle col^=quad<<4, 2 lanes/bank = free) -> 16B
// coalesced global stores (1 KB/wave-inst), replacing 128 scalar stores/thread
// with 16 vector stores/thread and killing sub-64B write amplification.
// ===========================================================================

#define BAR() asm volatile("s_barrier" ::: "memory")
#define VMC(n) asm volatile("s_waitcnt vmcnt(" #n ")" ::: "memory")
#define LGK0() asm volatile("s_waitcnt lgkmcnt(0)" ::: "memory")

template <bool OUTBF>
__device__ __forceinline__ void gemm256_8p(
    const u16* __restrict__ A, const u16* __restrict__ Bm,
    const float* __restrict__ bias, void* __restrict__ Cp,
    int gm0, int gn0, u16* sm) {
  const int tid = threadIdx.x;
  const int lane = tid & 63;
  const int w = tid >> 6;
  const int wm = w >> 2, wn = w & 3;       // 2 x 4 wave grid
  const int wr0 = wm * 128, wc0 = wn * 64; // per-wave 128x64 output
  const int lr = lane & 15, quad = lane >> 4;

  // staging decode: thread covers row chunk (sr, sc) of each 8KB load
  const int sr = tid >> 3;   // 0..63 (row within 64-row stripe)
  const int sc = tid & 7;    // 16B chunk within 128B row

  f32x4 acc[8][4];
#pragma unroll
  for (int i = 0; i < 8; i++)
#pragma unroll
    for (int j = 0; j < 4; j++) acc[i][j] = (f32x4){0.f, 0.f, 0.f, 0.f};

  bf16x8 aA[4][2];  // current A-half frags (4 mi x 2 kk)
  bf16x8 bB[4][2];  // all-B frags (4 ni x 2 kk), halves filled p0/p1, held

#define STAGE_A(buf, h, T) do {                                              \
    int k0_ = ((T) & 15) * 64;                                               \
    u16* lb_ = sm + (buf) * 16384;                                           \
    _Pragma("unroll")                                                        \
    for (int ld_ = 0; ld_ < 2; ld_++) {                                      \
      int row_ = ld_ * 128 + (h) * 64 + sr;      /* (row%128)<64 iff h==0 */ \
      int cs_ = (sc ^ (row_ & 7)) * 8;           /* pre-swizzled source */   \
      async_copy16(A + (size_t)(gm0 + row_) * 1024 + k0_ + cs_,              \
                   lb_ + row_ * 64 + sc * 8);                                \
    }                                                                        \
  } while (0)

#define STAGE_B(buf, bh, T) do {                                             \
    int k0_ = ((T) & 15) * 64;                                               \
    u16* lb_ = sm + 32768 + (buf) * 16384;                                   \
    _Pragma("unroll")                                                        \
    for (int ld_ = 0; ld_ < 2; ld_++) {                                      \
      int ri_ = ld_ * 64 + sr;                                               \
      int row_ = ((ri_ >> 5) << 6) + (bh) * 32 + (ri_ & 31);                 \
      int cs_ = (sc ^ (row_ & 7)) * 8;                                       \
      async_copy16(Bm + (size_t)(gn0 + row_) * 1024 + k0_ + cs_,             \
                   lb_ + row_ * 64 + sc * 8);                                \
    }                                                                        \
  } while (0)

#define READ_A(mh, buf) do {                                                 \
    const u16* lb_ = sm + (buf) * 16384;                                     \
    _Pragma("unroll")                                                        \
    for (int m4_ = 0; m4_ < 4; m4_++)                                        \
      _Pragma("unroll")                                                      \
      for (int kk_ = 0; kk_ < 2; kk_++) {                                    \
        int row_ = wr0 + ((mh) * 4 + m4_) * 16 + lr;                         \
        aA[m4_][kk_] = *(const bf16x8*)(lb_ + row_ * 64 +                    \
                         (((kk_ * 4 + quad) ^ (row_ & 7)) * 8));             \
      }                                                                      \
  } while (0)

#define READ_B(nh, buf) do {                                                 \
    const u16* lb_ = sm + 32768 + (buf) * 16384;                             \
    _Pragma("unroll")                                                        \
    for (int n2_ = 0; n2_ < 2; n2_++)                                        \
      _Pragma("unroll")                                                      \
      for (int kk_ = 0; kk_ < 2; kk_++) {                                    \
        int row_ = wc0 + ((nh) * 2 + n2_) * 16 + lr;                         \
        bB[(nh) * 2 + n2_][kk_] = *(const bf16x8*)(lb_ + row_ * 64 +         \
                         (((kk_ * 4 + quad) ^ (row_ & 7)) * 8));             \
      }                                                                      \
  } while (0)

#define MFMA16(mh, nh) do {                                                  \
    __builtin_amdgcn_s_setprio(1);                                           \
    _Pragma("unroll")                                                        \
    for (int m4_ = 0; m4_ < 4; m4_++)                                        \
      _Pragma("unroll")                                                      \
      for (int n2_ = 0; n2_ < 2; n2_++)                                      \
        _Pragma("unroll")                                                    \
        for (int kk_ = 0; kk_ < 2; kk_++)                                    \
          acc[(mh) * 4 + m4_][(nh) * 2 + n2_] =                              \
              __builtin_amdgcn_mfma_f32_16x16x32_bf16(                       \
                  aA[m4_][kk_], bB[(nh) * 2 + n2_][kk_],                     \
                  acc[(mh) * 4 + m4_][(nh) * 2 + n2_], 0, 0, 0);             \
    __builtin_amdgcn_s_setprio(0);                                           \
  } while (0)

  // ---- prologue: tile0 fully + tile1 {A0,B0,A1}; one counted wait ----------
  STAGE_A(0, 0, 0); STAGE_B(0, 0, 0); STAGE_A(0, 1, 0); STAGE_B(0, 1, 0);
  STAGE_A(1, 0, 1); STAGE_B(1, 0, 1); STAGE_A(1, 1, 1);
  VMC(6);   // tile0 fully landed; in flight: tile1.{A0,B0,A1}
  BAR();

  // ---- main loop: 8 iterations x (2 K-tiles = 8 phases) --------------------
  for (int i = 0; i < 8; i++) {
    const int T1 = 2 * i + 1, T2 = 2 * i + 2, T3 = 2 * i + 3;
    // phase 0: tile 2i (buf0), quadrant (mh0, nh0)
    READ_A(0, 0); READ_B(0, 0);
    STAGE_B(1, 1, T1);
    BAR(); MFMA16(0, 0); BAR();
    // phase 1: quadrant (0,1) -- reuse aA, read B-H1
    READ_B(1, 0);
    STAGE_A(0, 0, T2);
    BAR(); MFMA16(0, 1); BAR();
    // phase 2: quadrant (1,0) -- read A-H1, reuse held B-H0 frags
    READ_A(1, 0);
    STAGE_B(0, 0, T2);
    BAR(); MFMA16(1, 0); BAR();
    // phase 3: quadrant (1,1); counted vmcnt -> tile 2i+1 fully landed
    STAGE_A(0, 1, T2);
    VMC(6);
    BAR(); MFMA16(1, 1); BAR();
    // phase 4: tile 2i+1 (buf1), quadrant (0,0)
    READ_A(0, 1); READ_B(0, 1);
    STAGE_B(0, 1, T2);
    BAR(); MFMA16(0, 0); BAR();
    // phase 5
    READ_B(1, 1);
    STAGE_A(1, 0, T3);
    BAR(); MFMA16(0, 1); BAR();
    // phase 6
    READ_A(1, 1);
    STAGE_B(1, 0, T3);
    BAR(); MFMA16(1, 0); BAR();
    // phase 7: counted vmcnt -> tile 2i+2 fully landed
    STAGE_A(1, 1, T3);
    VMC(6);
    BAR(); MFMA16(1, 1); BAR();
  }
  VMC(0);  // drain wrap-around junk stages (they land in LDS)
  BAR();   // ...across ALL waves before epilogue reuses LDS

  // ---- epilogue: LDS repack -> coalesced stores ----------------------------
  // LDS layout: C(row,col) at sm[row*256 + (col ^ (((row>>2)&3)<<4))].
  // Writer: row = wr0+mi*16+quad*4+r -> (row>>2)&3 == quad; swizzled col =
  // wc0 + ((ni^quad)<<4) + lr -> banks (ni^quad)*8 + lr/2: 2 lanes/bank, free.
  if constexpr (OUTBF) {
    float bv[4];
#pragma unroll
    for (int ni = 0; ni < 4; ni++) bv[ni] = bias[gn0 + wc0 + ni * 16 + lr];
#pragma unroll
    for (int mi = 0; mi < 8; mi++)
#pragma unroll
      for (int ni = 0; ni < 4; ni++) {
        int sc_ = wc0 + ((ni ^ quad) << 4) + lr;
#pragma unroll
        for (int r = 0; r < 4; r++) {
          int row = wr0 + mi * 16 + quad * 4 + r;
          float val = acc[mi][ni][r] + bv[ni];
          sm[row * 256 + sc_] = (u16)((__builtin_bit_cast(u32, val) + 0x8000u) >> 16);
        }
      }
    LGK0(); BAR();
    u16* Cg = (u16*)Cp;
#pragma unroll
    for (int j = 0; j < 16; j++) {
      int id = j * 512 + tid;            // 8192 16B-chunks: 256 rows x 32
      int row = id >> 5, ch = id & 31;
      int q = (row >> 2) & 3;
      uint4 vv = *(const uint4*)&sm[row * 256 + ((ch * 8) ^ (q << 4))];
      *(uint4*)&Cg[(size_t)(gm0 + row) * 1024 + gn0 + ch * 8] = vv;
    }
  } else {
    // f32 out: two 128-row passes (128 rows x 256 f32 = 128 KiB = whole LDS).
    // Pass h covers mi = h*4..h*4+3; local row = wm*64 + (mi&3)*16 + quad*4+r.
    float* cf = (float*)sm;
    float bv[4];
#pragma unroll
    for (int ni = 0; ni < 4; ni++) bv[ni] = bias[gn0 + wc0 + ni * 16 + lr];
#pragma unroll
    for (int h = 0; h < 2; h++) {
#pragma unroll
      for (int m4 = 0; m4 < 4; m4++) {
        int mi = h * 4 + m4;
#pragma unroll
        for (int ni = 0; ni < 4; ni++) {
          int sc_ = wc0 + ((ni ^ quad) << 4) + lr;
#pragma unroll
          for (int r = 0; r < 4; r++) {
            int lrow = (wm << 6) + m4 * 16 + quad * 4 + r;
            cf[lrow * 256 + sc_] = acc[mi][ni][r] + bv[ni];
          }
        }
      }
      LGK0(); BAR();
      float* Cg = (float*)Cp;
#pragma unroll
      for (int j = 0; j < 16; j++) {
        int id = j * 512 + tid;          // 8192 16B-chunks: 128 rows x 64
        int lrow = id >> 6, ch = id & 63;
        int q = (lrow >> 2) & 3;
        float4 vv = *(const float4*)&cf[lrow * 256 + ((ch * 4) ^ (q << 4))];
        int grow = ((lrow >> 6) << 7) + (h << 6) + (lrow & 63);
        *(float4*)&Cg[(size_t)(gm0 + grow) * 1024 + gn0 + ch * 4] = vv;
      }
      if (h == 0) { LGK0(); BAR(); }   // pass-0 reads done before pass-1 writes
    }
  }
#undef STAGE_A
#undef STAGE_B
#undef READ_A
#undef READ_B
#undef MFMA16
}

// fused QKV projection, 8-phase path. 768 blocks (64m x 4n x 3z), 512 thr.
__global__ __launch_bounds__(512, 2) void gemm_qkv8(
    const u16* __restrict__ X, const u16* __restrict__ W,
    const float* __restrict__ b0, const float* __restrict__ b1,
    const float* __restrict__ b2, u16* __restrict__ out) {
  __shared__ alignas(16) u16 sm[65536];
  const int lin = blockIdx.x;
  const int c = lin & 7;        // XCD
  const int i = lin >> 3;       // 0..95
  const int z = i >> 5;         // tensor 0..2
  const int r = i & 31;
  const int m = c * 8 + (r >> 2);
  const int n = r & 3;
  const float* bias = (z == 0) ? b0 : (z == 1) ? b1 : b2;
  gemm256_8p<true>(X + (size_t)z * 16777216, W + (size_t)z * 1048576, bias,
                   out + (size_t)z * 16777216, m * 256, n * 256, sm);
}

__global__ __launch_bounds__(512, 2) void gemm_o8(
    const u16* __restrict__ X, const u16* __restrict__ W,
    const float* __restrict__ bias, float* __restrict__ C) {
  __shared__ alignas(16) u16 sm[65536];
  const int lin = blockIdx.x;   // 0..255
  const int c = lin & 7;
  const int i = lin >> 3;       // 0..31
  const int m = c * 8 + (i >> 2);
  const int n = i & 3;
  gemm256_8p<false>(X, W, bias, C, m * 256, n * 256, sm);
}

// ---- legacy 128^2 GEMM tile (kept only for the fp32-A fallback path) ------
template <bool AF32, bool OUTBF>
__device__ __forceinline__ void gemm_tile(const void* __restrict__ Ap,
                                          const u16* __restrict__ Bp,
                                          const float* __restrict__ bias,
                                          void* __restrict__ Cp,
                                          int m0, int n0, u16* As, u16* Bs) {
  constexpr int KD = 1024;
  constexpr int ND = 1024;
  const int t = threadIdx.x;
  const int lane = t & 63, w = t >> 6;
  const int wr = (w >> 1) * 64, wc = (w & 1) * 64;
  const int lr = lane & 15, quad = lane >> 4;
  f32x4 acc[4][4] = {};

  for (int k0 = 0; k0 < KD; k0 += 32) {
    __syncthreads();
#pragma unroll
    for (int i = 0; i < 2; i++) {
      int c = i * 256 + t;
      int r = c >> 2, c8 = (c & 3) * 8;
      async_copy16(Bp + ((size_t)(n0 + r) * KD + k0 + c8), &Bs[c * 8]);
    }
    if constexpr (AF32) {
      const float* Af = (const float*)Ap;
      const int r = t >> 2, c8 = (t & 3) * 8;
      const float4* s0 = (const float4*)(Af + (size_t)(m0 + r) * KD + k0 + c8);
      const float4* s1 = (const float4*)(Af + (size_t)(m0 + 64 + r) * KD + k0 + c8);
      float4 f0 = s0[0], f1 = s0[1];
      float4 f2 = s1[0], f3 = s1[1];
      uint4 u0 = { pk_bf16(f0.x, f0.y), pk_bf16(f0.z, f0.w),
                   pk_bf16(f1.x, f1.y), pk_bf16(f1.z, f1.w) };
      uint4 u1 = { pk_bf16(f2.x, f2.y), pk_bf16(f2.z, f2.w),
                   pk_bf16(f3.x, f3.y), pk_bf16(f3.z, f3.w) };
      *(uint4*)&As[t * 8] = u0;
      *(uint4*)&As[(256 + t) * 8] = u1;
    } else {
      const u16* Ab = (const u16*)Ap;
#pragma unroll
      for (int i = 0; i < 2; i++) {
        int c = i * 256 + t;
        int r = c >> 2, c8 = (c & 3) * 8;
        async_copy16(Ab + ((size_t)(m0 + r) * KD + k0 + c8), &As[c * 8]);
      }
    }
    __syncthreads();

    bf16x8 af[4], bfr[4];
#pragma unroll
    for (int mi = 0; mi < 4; mi++)
      af[mi] = *(const bf16x8*)&As[(wr + mi * 16 + lr) * 32 + quad * 8];
#pragma unroll
    for (int ni = 0; ni < 4; ni++)
      bfr[ni] = *(const bf16x8*)&Bs[(wc + ni * 16 + lr) * 32 + quad * 8];
#pragma unroll
    for (int mi = 0; mi < 4; mi++)
#pragma unroll
      for (int ni = 0; ni < 4; ni++)
        acc[mi][ni] = __builtin_amdgcn_mfma_f32_16x16x32_bf16(af[mi], bfr[ni], acc[mi][ni], 0, 0, 0);
  }

#pragma unroll
  for (int ni = 0; ni < 4; ni++) {
    int col = n0 + wc + ni * 16 + lr;
    float bv = bias[col];
#pragma unroll
    for (int mi = 0; mi < 4; mi++) {
      int row = m0 + wr + mi * 16 + quad * 4;
#pragma unroll
      for (int r = 0; r < 4; r++) {
        float val = acc[mi][ni][r] + bv;
        if constexpr (OUTBF) {
          ((u16*)Cp)[(size_t)(row + r) * ND + col] =
              (u16)((__builtin_bit_cast(u32, val) + 0x8000u) >> 16);
        } else {
          ((float*)Cp)[(size_t)(row + r) * ND + col] = val;
        }
      }
    }
  }
}

template <bool AF32>
__global__ __launch_bounds__(256) void gemm_qkv(
    const void* __restrict__ a0, const void* __restrict__ a1, const void* __restrict__ a2,
    const u16* __restrict__ W, const float* __restrict__ b0, const float* __restrict__ b1,
    const float* __restrict__ b2, u16* __restrict__ out) {
  __shared__ alignas(16) u16 As[128 * 32];
  __shared__ alignas(16) u16 Bs[128 * 32];
  const int lin = blockIdx.x;
  const int c = lin & 7;
  const int i = lin >> 3;
  const int z = i >> 7;
  const int r = i & 127;
  const int m = c * 16 + (r >> 3);
  const int n = r & 7;
  const void* A = (z == 0) ? a0 : (z == 1) ? a1 : a2;
  const float* bias = (z == 0) ? b0 : (z == 1) ? b1 : b2;
  gemm_tile<AF32, true>(A, W + (size_t)z * 1048576, bias, out + (size_t)z * 16777216,
                        m * 128, n * 128, As, Bs);
}

// ---- per-position head-mix attention (unchanged, verified) ----------------
__global__ __launch_bounds__(256) void attn_mix(
    const u16* __restrict__ Q, const u16* __restrict__ K,
    const u16* __restrict__ V, const int* __restrict__ mask,
    u16* __restrict__ X) {
  constexpr int RS = 72;
  __shared__ alignas(16) u16 qs[4][16 * RS];
  __shared__ alignas(16) u16 ks[4][16 * RS];
  __shared__ alignas(16) u16 vs[4][16 * RS];

  const int w = threadIdx.x >> 6;
  const int lane = threadIdx.x & 63;
  const int p = blockIdx.x * 4 + w;
  const size_t base = (size_t)p * 1024;

  {
    const uint4* Qg = (const uint4*)(Q + base);
    const uint4* Kg = (const uint4*)(K + base);
    const uint4* Vg = (const uint4*)(V + base);
#pragma unroll
    for (int h = 0; h < 2; h++) {
      int j = h * 64 + lane;
      int off = (j >> 3) * RS + (j & 7) * 8;
      *(uint4*)&qs[w][off] = Qg[j];
      *(uint4*)&ks[w][off] = Kg[j];
      *(uint4*)&vs[w][off] = Vg[j];
    }
  }
  const int mk = mask[p];

  const int qh = lane >> 2, g = lane & 3;
  float e0 = 0.f, e1 = 0.f, e2 = 0.f, e3 = 0.f;
  {
    const u16* qr = &qs[w][qh * RS];
    const u16* k0r = &ks[w][(g * 4 + 0) * RS];
    const u16* k1r = &ks[w][(g * 4 + 1) * RS];
    const u16* k2r = &ks[w][(g * 4 + 2) * RS];
    const u16* k3r = &ks[w][(g * 4 + 3) * RS];
#pragma unroll
    for (int c = 0; c < 8; c++) {
      F8 qf = unp8(*(const uint4*)&qr[c * 8]);
      F8 ka = unp8(*(const uint4*)&k0r[c * 8]);
      F8 kb = unp8(*(const uint4*)&k1r[c * 8]);
      F8 kc = unp8(*(const uint4*)&k2r[c * 8]);
      F8 kd = unp8(*(const uint4*)&k3r[c * 8]);
#pragma unroll
      for (int j = 0; j < 8; j++) {
        e0 += qf.f[j] * ka.f[j];
        e1 += qf.f[j] * kb.f[j];
        e2 += qf.f[j] * kc.f[j];
        e3 += qf.f[j] * kd.f[j];
      }
    }
  }
  const float sc = mk ? 0.03125f : 0.0f;
  float v0 = e0 * sc, v1 = e1 * sc, v2 = e2 * sc, v3 = e3 * sc;
  float mx = fmaxf(fmaxf(v0, v1), fmaxf(v2, v3));
  mx = fmaxf(mx, __shfl_xor(mx, 1, 64));
  mx = fmaxf(mx, __shfl_xor(mx, 2, 64));
  float p0 = __expf(v0 - mx), p1 = __expf(v1 - mx), p2 = __expf(v2 - mx), p3 = __expf(v3 - mx);
  float s = p0 + p1 + p2 + p3;
  s += __shfl_xor(s, 1, 64);
  s += __shfl_xor(s, 2, 64);
  float inv = 1.0f / s;
  float a0 = p0 * inv, a1 = p1 * inv, a2 = p2 * inv, a3 = p3 * inv;

  float xa[16];
#pragma unroll
  for (int i = 0; i < 16; i++) xa[i] = 0.f;
#pragma unroll
  for (int g2 = 0; g2 < 4; g2++) {
    int src = (lane & ~3) | g2;
    float w0 = __shfl(a0, src, 64);
    float w1 = __shfl(a1, src, 64);
    float w2 = __shfl(a2, src, 64);
    float w3 = __shfl(a3, src, 64);
    const float wv[4] = { w0, w1, w2, w3 };
#pragma unroll
    for (int j4 = 0; j4 < 4; j4++) {
      int kh = g2 * 4 + j4;
      float wgt = wv[j4];
      F8 va = unp8(*(const uint4*)&vs[w][kh * RS + g * 16]);
      F8 vb = unp8(*(const uint4*)&vs[w][kh * RS + g * 16 + 8]);
#pragma unroll
      for (int j = 0; j < 8; j++) {
        xa[j] += wgt * va.f[j];
        xa[8 + j] += wgt * vb.f[j];
      }
    }
  }
  uint4 o0 = { pk_bf16(xa[0], xa[1]), pk_bf16(xa[2], xa[3]),
               pk_bf16(xa[4], xa[5]), pk_bf16(xa[6], xa[7]) };
  uint4 o1 = { pk_bf16(xa[8], xa[9]), pk_bf16(xa[10], xa[11]),
               pk_bf16(xa[12], xa[13]), pk_bf16(xa[14], xa[15]) };
  uint4* Xp = (uint4*)(X + base);
  Xp[lane * 2] = o0;
  Xp[lane * 2 + 1] = o1;
}

extern "C" void kernel_launch(void* const* d_in, const int* in_sizes, int n_in,
                              void* d_out, int out_size, void* d_ws, size_t ws_size,
                              hipStream_t stream) {
  const float* q    = (const float*)d_in[0];
  const float* k    = (const float*)d_in[1];
  const float* v    = (const float*)d_in[2];
  const int*   mask = (const int*)d_in[3];
  const float* Wq   = (const float*)d_in[4];
  const float* bq   = (const float*)d_in[5];
  const float* Wk   = (const float*)d_in[6];
  const float* bk   = (const float*)d_in[7];
  const float* Wv   = (const float*)d_in[8];
  const float* bv   = (const float*)d_in[9];
  const float* Wo   = (const float*)d_in[10];
  const float* bo   = (const float*)d_in[11];

  u16* wsb = (u16*)d_ws;
  const bool big = ws_size >= 209715200ull;  // 200 MiB path

  if (big) {
    // layout (u16 elems): Wqkv[3M] Wo[1M] qb/kb/vb[3x16.78M] Q/K/V[3x16.78M]; X aliases qb
    u16* Wqkv = wsb;
    u16* Wob  = wsb + 3145728;
    u16* qb   = wsb + 4194304;
    u16* Qb   = wsb + 54525952;
    u16* Kb   = Qb + 16777216;
    u16* Vb   = Kb + 16777216;
    u16* Xb   = qb;  // qb/kb/vb dead after gemm_qkv8
    cvt_w4<<<dim3(1024, 4), 256, 0, stream>>>(Wq, Wk, Wv, Wo, wsb);
    cvt_in3<<<dim3(16384, 3), 256, 0, stream>>>(q, k, v, qb);
    gemm_qkv8<<<768, 512, 0, stream>>>(qb, Wqkv, bq, bk, bv, Qb);
    attn_mix<<<4096, 256, 0, stream>>>(Qb, Kb, Vb, mask, Xb);
    gemm_o8<<<256, 512, 0, stream>>>(Xb, Wob, bo, (float*)d_out);
  } else {
    // fallback: fp32-A in-staging path (142.6 MB)
    u16* Wqkv = wsb;
    u16* Wob  = wsb + 3145728;
    u16* Qb   = wsb + 4194304;
    u16* Kb   = Qb + 16777216;
    u16* Vb   = Kb + 16777216;
    u16* Xb   = Vb + 16777216;
    cvt_w4<<<dim3(1024, 4), 256, 0, stream>>>(Wq, Wk, Wv, Wo, wsb);
    gemm_qkv<true><<<3072, 256, 0, stream>>>(q, k, v, Wqkv, bq, bk, bv, Qb);
    attn_mix<<<4096, 256, 0, stream>>>(Qb, Kb, Vb, mask, Xb);
    gemm_o8<<<256, 512, 0, stream>>>(Xb, Wob, bo, (float*)d_out);
  }
}